// Round 13
// baseline (745.384 us; speedup 1.0000x reference)
//
#include <hip/hip_runtime.h>

typedef _Float16 f16;
typedef _Float16 f16x8 __attribute__((ext_vector_type(8)));
typedef float f32x16 __attribute__((ext_vector_type(16)));
typedef unsigned long long u64;

#define NB 5
#define DIN 100
#define NT 512
#define GRID 256
#define NWAVES (GRID * 8)

// fragment ids: W1 = [ks0..6][mt0..1] -> 14, W2 -> 8, heads: q*16 + layer*8 + ks*2 + mt
#define FID_W2 14
#define FID_HD 22
#define NFID   (FID_HD + NB * 16)   // 102
#define NENT   (NFID * 64)          // 6528 f16x8 entries

// A-frag layout (32x32x16): lane l holds W[k = 16*ks + 8*(l>>5) + e][feat = 32*mt + (l&31)]
__global__ __launch_bounds__(256)
void prepack_kernel(const float* __restrict__ dW1, const float* __restrict__ dW2,
                    const float* __restrict__ hw1, const float* __restrict__ hw2,
                    f16x8* __restrict__ pw)
{
    int E = blockIdx.x * 256 + threadIdx.x;
    if (E >= NENT) return;
    int lane = E & 63, fid = E >> 6;
    const float* src; int ks, mt, kmax;
    if (fid < FID_W2)      { int f = fid;          ks = f >> 1; mt = f & 1; src = dW1; kmax = 100; }
    else if (fid < FID_HD) { int f = fid - FID_W2; ks = f >> 1; mt = f & 1; src = dW2; kmax = 64; }
    else {
        int f = fid - FID_HD; int q = f >> 4; int r = f & 15;
        int layer = r >> 3; int rr = r & 7; ks = rr >> 1; mt = rr & 1;
        src = (layer ? hw2 : hw1) + q * 4096; kmax = 64;
    }
    f16x8 v;
    #pragma unroll
    for (int e = 0; e < 8; ++e) {
        int k = 16 * ks + 8 * (lane >> 5) + e;
        int m = 32 * mt + (lane & 31);
        v[e] = (k < kmax) ? (f16)src[k * 64 + m] : (f16)0.f;
    }
    pw[E] = v;
}

__device__ __forceinline__ f32x16 mfma32(f16x8 a, f16x8 b, f32x16 c) {
    return __builtin_amdgcn_mfma_f32_32x32x16_f16(a, b, c, 0, 0, 0);
}
__device__ __forceinline__ f32x16 vzero() {
    f32x16 z;
    #pragma unroll
    for (int i = 0; i < 16; ++i) z[i] = 0.f;
    return z;
}
__device__ __forceinline__ unsigned pk2(float a, float b) {   // rne f16 pair pack
    union { f16 h[2]; unsigned u; } z; z.h[0] = (f16)a; z.h[1] = (f16)b; return z.u;
}
__device__ __forceinline__ f16x8 frag4(unsigned a, unsigned b, unsigned c, unsigned d) {
    union { unsigned u[4]; f16x8 v; } z; z.u[0]=a; z.u[1]=b; z.u[2]=c; z.u[3]=d; return z.v;
}

#define EPI8T(W, A, BIAS, TW, RT, OFF) { \
    const float4* bp_ = (const float4*)((BIAS) + (OFF)); \
    const float4* tp_ = (const float4*)((TW) + (OFF)); \
    float4 b0_=bp_[0], b1_=bp_[2], b2_=bp_[4], b3_=bp_[6]; \
    float4 t0_=tp_[0], t1_=tp_[2], t2_=tp_[4], t3_=tp_[6]; \
    W[0]=pk2(fmaxf(A[0]+b0_.x+(RT)*t0_.x,0.f), fmaxf(A[1]+b0_.y+(RT)*t0_.y,0.f)); \
    W[1]=pk2(fmaxf(A[2]+b0_.z+(RT)*t0_.z,0.f), fmaxf(A[3]+b0_.w+(RT)*t0_.w,0.f)); \
    W[2]=pk2(fmaxf(A[4]+b1_.x+(RT)*t1_.x,0.f), fmaxf(A[5]+b1_.y+(RT)*t1_.y,0.f)); \
    W[3]=pk2(fmaxf(A[6]+b1_.z+(RT)*t1_.z,0.f), fmaxf(A[7]+b1_.w+(RT)*t1_.w,0.f)); \
    W[4]=pk2(fmaxf(A[8]+b2_.x+(RT)*t2_.x,0.f), fmaxf(A[9]+b2_.y+(RT)*t2_.y,0.f)); \
    W[5]=pk2(fmaxf(A[10]+b2_.z+(RT)*t2_.z,0.f), fmaxf(A[11]+b2_.w+(RT)*t2_.w,0.f)); \
    W[6]=pk2(fmaxf(A[12]+b3_.x+(RT)*t3_.x,0.f), fmaxf(A[13]+b3_.y+(RT)*t3_.y,0.f)); \
    W[7]=pk2(fmaxf(A[14]+b3_.z+(RT)*t3_.z,0.f), fmaxf(A[15]+b3_.w+(RT)*t3_.w,0.f)); }

#define EPI8B(W, A, BIAS, OFF) { \
    const float4* bp_ = (const float4*)((BIAS) + (OFF)); \
    float4 b0_=bp_[0], b1_=bp_[2], b2_=bp_[4], b3_=bp_[6]; \
    W[0]=pk2(fmaxf(A[0]+b0_.x,0.f), fmaxf(A[1]+b0_.y,0.f)); \
    W[1]=pk2(fmaxf(A[2]+b0_.z,0.f), fmaxf(A[3]+b0_.w,0.f)); \
    W[2]=pk2(fmaxf(A[4]+b1_.x,0.f), fmaxf(A[5]+b1_.y,0.f)); \
    W[3]=pk2(fmaxf(A[6]+b1_.z,0.f), fmaxf(A[7]+b1_.w,0.f)); \
    W[4]=pk2(fmaxf(A[8]+b2_.x,0.f), fmaxf(A[9]+b2_.y,0.f)); \
    W[5]=pk2(fmaxf(A[10]+b2_.z,0.f), fmaxf(A[11]+b2_.w,0.f)); \
    W[6]=pk2(fmaxf(A[12]+b3_.x,0.f), fmaxf(A[13]+b3_.y,0.f)); \
    W[7]=pk2(fmaxf(A[14]+b3_.z,0.f), fmaxf(A[15]+b3_.w,0.f)); }

#define MKB(dst, Wm, jb) { \
    unsigned s0_=__shfl_xor(Wm[jb+0],32,64), s1_=__shfl_xor(Wm[jb+1],32,64); \
    unsigned s2_=__shfl_xor(Wm[jb+2],32,64), s3_=__shfl_xor(Wm[jb+3],32,64); \
    dst = frag4(lo ? Wm[jb+0] : s2_, lo ? Wm[jb+1] : s3_, \
                lo ? s0_ : Wm[jb+2], lo ? s1_ : Wm[jb+3]); }

#define ACC16(P, A, B2, T2, W3, RT, OFF) { \
    const float4* bb_=(const float4*)((B2)+(OFF)); const float4* tt_=(const float4*)((T2)+(OFF)); \
    const float4* ww_=(const float4*)((W3)+(OFF)); \
    float4 b0_=bb_[0],b1_=bb_[2],b2_=bb_[4],b3_=bb_[6]; \
    float4 t0_=tt_[0],t1_=tt_[2],t2_=tt_[4],t3_=tt_[6]; \
    float4 w0_=ww_[0],w1_=ww_[2],w2_=ww_[4],w3_=ww_[6]; \
    P += fmaxf(A[0]+b0_.x+(RT)*t0_.x,0.f)*w0_.x + fmaxf(A[1]+b0_.y+(RT)*t0_.y,0.f)*w0_.y \
       + fmaxf(A[2]+b0_.z+(RT)*t0_.z,0.f)*w0_.z + fmaxf(A[3]+b0_.w+(RT)*t0_.w,0.f)*w0_.w \
       + fmaxf(A[4]+b1_.x+(RT)*t1_.x,0.f)*w1_.x + fmaxf(A[5]+b1_.y+(RT)*t1_.y,0.f)*w1_.y \
       + fmaxf(A[6]+b1_.z+(RT)*t1_.z,0.f)*w1_.z + fmaxf(A[7]+b1_.w+(RT)*t1_.w,0.f)*w1_.w \
       + fmaxf(A[8]+b2_.x+(RT)*t2_.x,0.f)*w2_.x + fmaxf(A[9]+b2_.y+(RT)*t2_.y,0.f)*w2_.y \
       + fmaxf(A[10]+b2_.z+(RT)*t2_.z,0.f)*w2_.z + fmaxf(A[11]+b2_.w+(RT)*t2_.w,0.f)*w2_.w \
       + fmaxf(A[12]+b3_.x+(RT)*t3_.x,0.f)*w3_.x + fmaxf(A[13]+b3_.y+(RT)*t3_.y,0.f)*w3_.y \
       + fmaxf(A[14]+b3_.z+(RT)*t3_.z,0.f)*w3_.z + fmaxf(A[15]+b3_.w+(RT)*t3_.w,0.f)*w3_.w; }

__global__ __launch_bounds__(NT, 2)
void drnet_main(const float* __restrict__ t, const float* __restrict__ x,
                const float* __restrict__ db1, const float* __restrict__ db2,
                const float* __restrict__ hb1, const float* __restrict__ htw1,
                const float* __restrict__ hb2, const float* __restrict__ htw2,
                const float* __restrict__ hw3, const float* __restrict__ htw3,
                const float* __restrict__ hb3,
                const f16x8* __restrict__ pw,
                float* __restrict__ out, int N, int NG)
{
    __shared__ __align__(16) f16x8 swts[NENT];          // 102 KB: all weight frags
    __shared__ __align__(16) float sb1f[64], sb2f[64];
    __shared__ __align__(16) float shb1[NB*64], shw1t[NB*64], shb2[NB*64], shw2t[NB*64], sw3f[NB*64];
    __shared__ float shtw3[NB], shb3[NB];
    __shared__ unsigned short ssrt[8][64];
    __shared__ float sstv[8][64];
    __shared__ float sout[8][64];

    const int tid = threadIdx.x;
    const int lane = tid & 63;
    const int wv = tid >> 6;
    const int hi = lane >> 5;
    const int sm = lane & 31;
    const bool lo = (hi == 0);

    for (int p = tid; p < 64; p += NT) { sb1f[p] = db1[p]; sb2f[p] = db2[p]; }
    for (int p = tid; p < NB*64; p += NT) {
        shb1[p] = hb1[p]; shw1t[p] = htw1[p];
        shb2[p] = hb2[p]; shw2t[p] = htw2[p];
        sw3f[p] = hw3[p];
    }
    if (tid < NB) { shtw3[tid] = htw3[tid]; shb3[tid] = hb3[tid]; }
    for (int p = tid; p < NENT; p += NT)
        ((float4*)swts)[p] = ((const float4*)pw)[p];
    __syncthreads();   // ONLY barrier; the main loop is fully wave-autonomous

    #define TF(fid) swts[(fid)*64 + lane]

    auto do_tile = [&](const f16x8* xb, int li, int rq, float rt, int qlo, int qhiR) {
        if (qlo >= NB) return;
        const int qhi = min(qhiR, NB - 1);

        f32x16 a0 = vzero(), a1 = vzero();
        #pragma unroll
        for (int ks = 0; ks < 7; ++ks) {
            a0 = mfma32(TF(ks*2 + 0), xb[ks], a0);
            a1 = mfma32(TF(ks*2 + 1), xb[ks], a1);
        }
        unsigned WA[8], WB[8];
        EPI8B(WA, a0, sb1f, 4*hi);
        EPI8B(WB, a1, sb1f, 32 + 4*hi);
        f16x8 hb0, hb1_, hb2_, hb3_;
        MKB(hb0, WA, 0); MKB(hb1_, WA, 4); MKB(hb2_, WB, 0); MKB(hb3_, WB, 4);

        f32x16 c0 = vzero(), c1 = vzero();
        c0 = mfma32(TF(FID_W2+0), hb0, c0);  c1 = mfma32(TF(FID_W2+1), hb0, c1);
        c0 = mfma32(TF(FID_W2+2), hb1_, c0); c1 = mfma32(TF(FID_W2+3), hb1_, c1);
        c0 = mfma32(TF(FID_W2+4), hb2_, c0); c1 = mfma32(TF(FID_W2+5), hb2_, c1);
        c0 = mfma32(TF(FID_W2+6), hb3_, c0); c1 = mfma32(TF(FID_W2+7), hb3_, c1);
        unsigned UA[8], UB[8];
        EPI8B(UA, c0, sb2f, 4*hi);
        EPI8B(UB, c1, sb2f, 32 + 4*hi);
        f16x8 g0, g1, g2, g3;
        MKB(g0, UA, 0); MKB(g1, UA, 4); MKB(g2, UB, 0); MKB(g3, UB, 4);

        #pragma unroll 1
        for (int q = qlo; q <= qhi; ++q) {
            const int hf = FID_HD + q * 16;
            f32x16 d0 = vzero(), d1 = vzero();
            d0 = mfma32(TF(hf+0), g0, d0);  d1 = mfma32(TF(hf+1), g0, d1);
            d0 = mfma32(TF(hf+2), g1, d0);  d1 = mfma32(TF(hf+3), g1, d1);
            d0 = mfma32(TF(hf+4), g2, d0);  d1 = mfma32(TF(hf+5), g2, d1);
            d0 = mfma32(TF(hf+6), g3, d0);  d1 = mfma32(TF(hf+7), g3, d1);
            unsigned VA[8], VB[8];
            EPI8T(VA, d0, shb1 + q*64, shw1t + q*64, rt, 4*hi);
            EPI8T(VB, d1, shb1 + q*64, shw1t + q*64, rt, 32 + 4*hi);
            f16x8 e0, e1, e2, e3;
            MKB(e0, VA, 0); MKB(e1, VA, 4); MKB(e2, VB, 0); MKB(e3, VB, 4);

            f32x16 f0 = vzero(), f1 = vzero();
            f0 = mfma32(TF(hf+8),  e0, f0);  f1 = mfma32(TF(hf+9),  e0, f1);
            f0 = mfma32(TF(hf+10), e1, f0);  f1 = mfma32(TF(hf+11), e1, f1);
            f0 = mfma32(TF(hf+12), e2, f0);  f1 = mfma32(TF(hf+13), e2, f1);
            f0 = mfma32(TF(hf+14), e3, f0);  f1 = mfma32(TF(hf+15), e3, f1);

            float part = 0.f;
            ACC16(part, f0, shb2 + q*64, shw2t + q*64, sw3f + q*64, rt, 4*hi);
            ACC16(part, f1, shb2 + q*64, shw2t + q*64, sw3f + q*64, rt, 32 + 4*hi);
            part += __shfl_xor(part, 32, 64);
            if (lo && rq == q)
                sout[wv][li] = part + rt * shtw3[q] + shb3[q];
        }
    };

    auto sortw = [&](int gn, float tvn) {
        const int i0 = gn * 64 + lane;
        const int qme = (i0 < N) ? min((int)(tvn * 5.0f), NB - 1) : NB;
        const u64 lowm = (1ull << lane) - 1ull;
        int pos = 0;
        #pragma unroll
        for (int b = 0; b <= NB; ++b) {
            u64 mb = __ballot(qme == b);
            int ca = __popcll(mb), cb = __popcll(mb & lowm);
            pos += (b < qme) ? ca : ((b == qme) ? cb : 0);
        }
        ssrt[wv][pos] = (unsigned short)(lane | (qme << 8));
        sstv[wv][pos] = tvn;
        __asm__ volatile("s_waitcnt lgkmcnt(0)" ::: "memory");
    };

    auto issue_x = [&](float4* r, int gn, int li) {
        const float4* xp = (const float4*)(x + (size_t)min(gn * 64 + li, N - 1) * DIN);
        #pragma unroll
        for (int ks = 0; ks < 6; ++ks) { r[2*ks] = xp[4*ks + 2*hi]; r[2*ks+1] = xp[4*ks + 2*hi + 1]; }
        r[12] = lo ? xp[24] : make_float4(0.f, 0.f, 0.f, 0.f);
    };

    auto convert = [&](f16x8* xb, const float4* r) {
        #pragma unroll
        for (int ks = 0; ks < 6; ++ks)
            xb[ks] = frag4(pk2(r[2*ks].x, r[2*ks].y),   pk2(r[2*ks].z, r[2*ks].w),
                           pk2(r[2*ks+1].x, r[2*ks+1].y), pk2(r[2*ks+1].z, r[2*ks+1].w));
        xb[6] = frag4(pk2(r[12].x, r[12].y), pk2(r[12].z, r[12].w), 0u, 0u);
    };

    const int gw = blockIdx.x * 8 + wv;
    const int S = NWAVES;

    float4 raw0[13], raw1[13];
    float treg = 0.f;
    int g = gw;
    if (g < NG) {
        treg = t[min(g * 64 + lane, N - 1)];
        sortw(g, treg);
        { int li = ssrt[wv][sm] & 63; issue_x(raw0, g, li); }
        { int gn = g + S; treg = (gn < NG) ? t[min(gn * 64 + lane, N - 1)] : 0.f; }
    }

    #pragma unroll 1
    for (; g < NG; g += S) {
        const unsigned short pk0 = ssrt[wv][sm], pk1 = ssrt[wv][32 + sm];
        const int li0 = pk0 & 63, rq0 = pk0 >> 8;
        const int li1 = pk1 & 63, rq1 = pk1 >> 8;
        const float rt0 = sstv[wv][sm], rt1 = sstv[wv][32 + sm];
        const int qlo0 = ssrt[wv][0]  >> 8, qh0 = ssrt[wv][31] >> 8;
        const int qlo1 = ssrt[wv][32] >> 8, qh1 = ssrt[wv][63] >> 8;

        issue_x(raw1, g, li1);
        f16x8 xb0[7], xb1[7];
        convert(xb0, raw0);
        __builtin_amdgcn_sched_barrier(0);
        do_tile(xb0, li0, rq0, rt0, qlo0, qh0);
        __builtin_amdgcn_sched_barrier(0);

        const bool last = (g + S >= NG);
        if (!last) {
            sortw(g + S, treg);
            { int gn2 = g + 2 * S; treg = (gn2 < NG) ? t[min(gn2 * 64 + lane, N - 1)] : 0.f; }
            { int li = ssrt[wv][sm] & 63; issue_x(raw0, g + S, li); }
            __builtin_amdgcn_sched_barrier(0);
        }
        convert(xb1, raw1);
        do_tile(xb1, li1, rq1, rt1, qlo1, qh1);

        __asm__ volatile("s_waitcnt lgkmcnt(0)" ::: "memory");
        const int ig = g * 64 + lane;
        if (ig < N) out[ig] = sout[wv][lane];
    }
    #undef TF
}

// ================= MEASUREMENT PROBES (write only to d_ws sink) =================
// Probe 1: coalesced grid-stride float4 read stream over x, 5 passes (2 GB).
#define PCOAL_GRID 2048
__global__ __launch_bounds__(256)
void probe_coal(const float4* __restrict__ x4, float* __restrict__ sink, int nf4)
{
    float acc = 0.f;
    #pragma unroll 1
    for (int rep = 0; rep < 5; ++rep) {
        #pragma unroll 1
        for (size_t i = (size_t)blockIdx.x * 256 + threadIdx.x + (size_t)rep;
             i < (size_t)nf4; i += (size_t)PCOAL_GRID * 256) {
            float4 v = x4[i];
            acc += v.x + v.y + v.z + v.w;
        }
    }
    sink[(size_t)blockIdx.x * 256 + threadIdx.x] = acc;
}

// Probe 2: r8's exact gather shape (32 scattered 400B rows / instr within 64-row
// windows, 16B/lane), 5 passes (2 GB), zero compute.
__global__ __launch_bounds__(512)
void probe_gath(const float* __restrict__ x, float* __restrict__ sink, int N, int NG)
{
    const int tid = threadIdx.x, lane = tid & 63, wv = tid >> 6;
    const int hi = lane >> 5, sm = lane & 31;
    const bool lo = (hi == 0);
    const int gw = blockIdx.x * 8 + wv;
    float acc = 0.f;
    #pragma unroll 1
    for (int rep = 0; rep < 5; ++rep) {
        #pragma unroll 1
        for (int g = gw; g < NG; g += 2048) {
            #pragma unroll
            for (int half = 0; half < 2; ++half) {
                const int li = ((sm + half * 32) * 23 + rep) & 63;   // bijective scatter
                const float4* xp = (const float4*)(x + (size_t)min(g * 64 + li, N - 1) * DIN);
                float4 r[13];
                #pragma unroll
                for (int ks = 0; ks < 6; ++ks) { r[2*ks] = xp[4*ks + 2*hi]; r[2*ks+1] = xp[4*ks + 2*hi + 1]; }
                r[12] = lo ? xp[24] : make_float4(0.f, 0.f, 0.f, 0.f);
                #pragma unroll
                for (int j = 0; j < 13; ++j) acc += r[j].x + r[j].y + r[j].z + r[j].w;
            }
        }
    }
    sink[(size_t)blockIdx.x * 512 + tid] = acc;
}

extern "C" void kernel_launch(void* const* d_in, const int* in_sizes, int n_in,
                              void* d_out, int out_size, void* d_ws, size_t ws_size,
                              hipStream_t stream) {
    const float* t    = (const float*)d_in[0];
    const float* x    = (const float*)d_in[1];
    const float* dW1  = (const float*)d_in[2];
    const float* db1  = (const float*)d_in[3];
    const float* dW2  = (const float*)d_in[4];
    const float* db2  = (const float*)d_in[5];
    const float* hw1  = (const float*)d_in[6];
    const float* htw1 = (const float*)d_in[7];
    const float* hb1  = (const float*)d_in[8];
    const float* hw2  = (const float*)d_in[9];
    const float* htw2 = (const float*)d_in[10];
    const float* hb2  = (const float*)d_in[11];
    const float* hw3  = (const float*)d_in[12];
    const float* htw3 = (const float*)d_in[13];
    const float* hb3  = (const float*)d_in[14];
    float* out = (float*)d_out;

    const int N = in_sizes[0];
    const int NG = (N + 63) / 64;
    char* ws = (char*)d_ws;
    f16x8* pw = (f16x8*)ws;                                 // 104,448 B
    float* sinkA = (float*)(ws + 160 * 1024);               // 2 MB
    float* sinkB = (float*)(ws + 160 * 1024 + 2 * 1024 * 1024);  // 4 MB

    prepack_kernel<<<(NENT + 255) / 256, 256, 0, stream>>>(dW1, dW2, hw1, hw2, pw);
    drnet_main<<<GRID, NT, 0, stream>>>(t, x, db1, db2, hb1, htw1, hb2, htw2,
                                        hw3, htw3, hb3, pw, out, N, NG);
    // --- measurement probes (one-round diagnostic; appended after real work) ---
    probe_coal<<<PCOAL_GRID, 256, 0, stream>>>((const float4*)x, sinkA, N * 25);
    probe_gath<<<256, 512, 0, stream>>>(x, sinkB, N, NG);
}

// Round 14
// 150.618 us; speedup vs baseline: 4.9488x; 4.9488x over previous
//
#include <hip/hip_runtime.h>

typedef _Float16 f16;
typedef _Float16 f16x8 __attribute__((ext_vector_type(8)));
typedef float f32x16 __attribute__((ext_vector_type(16)));
typedef unsigned long long u64;

#define NB 5
#define DIN 100
#define NT 512
#define GRID 256
#define NWAVES (GRID * 8)

// fragment ids: W1 = [ks0..6][mt0..1] -> 14, W2 -> 8, heads: q*16 + layer*8 + ks*2 + mt
#define FID_W2 14
#define FID_HD 22
#define NFID   (FID_HD + NB * 16)   // 102
#define NENT   (NFID * 64)          // 6528 f16x8 entries

// A-frag layout (32x32x16): lane l holds W[k = 16*ks + 8*(l>>5) + e][feat = 32*mt + (l&31)]
__global__ __launch_bounds__(256)
void prepack_kernel(const float* __restrict__ dW1, const float* __restrict__ dW2,
                    const float* __restrict__ hw1, const float* __restrict__ hw2,
                    f16x8* __restrict__ pw)
{
    int E = blockIdx.x * 256 + threadIdx.x;
    if (E >= NENT) return;
    int lane = E & 63, fid = E >> 6;
    const float* src; int ks, mt, kmax;
    if (fid < FID_W2)      { int f = fid;          ks = f >> 1; mt = f & 1; src = dW1; kmax = 100; }
    else if (fid < FID_HD) { int f = fid - FID_W2; ks = f >> 1; mt = f & 1; src = dW2; kmax = 64; }
    else {
        int f = fid - FID_HD; int q = f >> 4; int r = f & 15;
        int layer = r >> 3; int rr = r & 7; ks = rr >> 1; mt = rr & 1;
        src = (layer ? hw2 : hw1) + q * 4096; kmax = 64;
    }
    f16x8 v;
    #pragma unroll
    for (int e = 0; e < 8; ++e) {
        int k = 16 * ks + 8 * (lane >> 5) + e;
        int m = 32 * mt + (lane & 31);
        v[e] = (k < kmax) ? (f16)src[k * 64 + m] : (f16)0.f;
    }
    pw[E] = v;
}

__device__ __forceinline__ f32x16 mfma32(f16x8 a, f16x8 b, f32x16 c) {
    return __builtin_amdgcn_mfma_f32_32x32x16_f16(a, b, c, 0, 0, 0);
}
__device__ __forceinline__ f32x16 vzero() {
    f32x16 z;
    #pragma unroll
    for (int i = 0; i < 16; ++i) z[i] = 0.f;
    return z;
}
__device__ __forceinline__ unsigned pk2(float a, float b) {   // rne f16 pair pack
    union { f16 h[2]; unsigned u; } z; z.h[0] = (f16)a; z.h[1] = (f16)b; return z.u;
}
__device__ __forceinline__ f16x8 frag4(unsigned a, unsigned b, unsigned c, unsigned d) {
    union { unsigned u[4]; f16x8 v; } z; z.u[0]=a; z.u[1]=b; z.u[2]=c; z.u[3]=d; return z.v;
}

#define EPI8T(W, A, BIAS, TW, RT, OFF) { \
    const float4* bp_ = (const float4*)((BIAS) + (OFF)); \
    const float4* tp_ = (const float4*)((TW) + (OFF)); \
    float4 b0_=bp_[0], b1_=bp_[2], b2_=bp_[4], b3_=bp_[6]; \
    float4 t0_=tp_[0], t1_=tp_[2], t2_=tp_[4], t3_=tp_[6]; \
    W[0]=pk2(fmaxf(A[0]+b0_.x+(RT)*t0_.x,0.f), fmaxf(A[1]+b0_.y+(RT)*t0_.y,0.f)); \
    W[1]=pk2(fmaxf(A[2]+b0_.z+(RT)*t0_.z,0.f), fmaxf(A[3]+b0_.w+(RT)*t0_.w,0.f)); \
    W[2]=pk2(fmaxf(A[4]+b1_.x+(RT)*t1_.x,0.f), fmaxf(A[5]+b1_.y+(RT)*t1_.y,0.f)); \
    W[3]=pk2(fmaxf(A[6]+b1_.z+(RT)*t1_.z,0.f), fmaxf(A[7]+b1_.w+(RT)*t1_.w,0.f)); \
    W[4]=pk2(fmaxf(A[8]+b2_.x+(RT)*t2_.x,0.f), fmaxf(A[9]+b2_.y+(RT)*t2_.y,0.f)); \
    W[5]=pk2(fmaxf(A[10]+b2_.z+(RT)*t2_.z,0.f), fmaxf(A[11]+b2_.w+(RT)*t2_.w,0.f)); \
    W[6]=pk2(fmaxf(A[12]+b3_.x+(RT)*t3_.x,0.f), fmaxf(A[13]+b3_.y+(RT)*t3_.y,0.f)); \
    W[7]=pk2(fmaxf(A[14]+b3_.z+(RT)*t3_.z,0.f), fmaxf(A[15]+b3_.w+(RT)*t3_.w,0.f)); }

#define EPI8B(W, A, BIAS, OFF) { \
    const float4* bp_ = (const float4*)((BIAS) + (OFF)); \
    float4 b0_=bp_[0], b1_=bp_[2], b2_=bp_[4], b3_=bp_[6]; \
    W[0]=pk2(fmaxf(A[0]+b0_.x,0.f), fmaxf(A[1]+b0_.y,0.f)); \
    W[1]=pk2(fmaxf(A[2]+b0_.z,0.f), fmaxf(A[3]+b0_.w,0.f)); \
    W[2]=pk2(fmaxf(A[4]+b1_.x,0.f), fmaxf(A[5]+b1_.y,0.f)); \
    W[3]=pk2(fmaxf(A[6]+b1_.z,0.f), fmaxf(A[7]+b1_.w,0.f)); \
    W[4]=pk2(fmaxf(A[8]+b2_.x,0.f), fmaxf(A[9]+b2_.y,0.f)); \
    W[5]=pk2(fmaxf(A[10]+b2_.z,0.f), fmaxf(A[11]+b2_.w,0.f)); \
    W[6]=pk2(fmaxf(A[12]+b3_.x,0.f), fmaxf(A[13]+b3_.y,0.f)); \
    W[7]=pk2(fmaxf(A[14]+b3_.z,0.f), fmaxf(A[15]+b3_.w,0.f)); }

#define MKB(dst, Wm, jb) { \
    unsigned s0_=__shfl_xor(Wm[jb+0],32,64), s1_=__shfl_xor(Wm[jb+1],32,64); \
    unsigned s2_=__shfl_xor(Wm[jb+2],32,64), s3_=__shfl_xor(Wm[jb+3],32,64); \
    dst = frag4(lo ? Wm[jb+0] : s2_, lo ? Wm[jb+1] : s3_, \
                lo ? s0_ : Wm[jb+2], lo ? s1_ : Wm[jb+3]); }

#define ACC16(P, A, B2, T2, W3, RT, OFF) { \
    const float4* bb_=(const float4*)((B2)+(OFF)); const float4* tt_=(const float4*)((T2)+(OFF)); \
    const float4* ww_=(const float4*)((W3)+(OFF)); \
    float4 b0_=bb_[0],b1_=bb_[2],b2_=bb_[4],b3_=bb_[6]; \
    float4 t0_=tt_[0],t1_=tt_[2],t2_=tt_[4],t3_=tt_[6]; \
    float4 w0_=ww_[0],w1_=ww_[2],w2_=ww_[4],w3_=ww_[6]; \
    P += fmaxf(A[0]+b0_.x+(RT)*t0_.x,0.f)*w0_.x + fmaxf(A[1]+b0_.y+(RT)*t0_.y,0.f)*w0_.y \
       + fmaxf(A[2]+b0_.z+(RT)*t0_.z,0.f)*w0_.z + fmaxf(A[3]+b0_.w+(RT)*t0_.w,0.f)*w0_.w \
       + fmaxf(A[4]+b1_.x+(RT)*t1_.x,0.f)*w1_.x + fmaxf(A[5]+b1_.y+(RT)*t1_.y,0.f)*w1_.y \
       + fmaxf(A[6]+b1_.z+(RT)*t1_.z,0.f)*w1_.z + fmaxf(A[7]+b1_.w+(RT)*t1_.w,0.f)*w1_.w \
       + fmaxf(A[8]+b2_.x+(RT)*t2_.x,0.f)*w2_.x + fmaxf(A[9]+b2_.y+(RT)*t2_.y,0.f)*w2_.y \
       + fmaxf(A[10]+b2_.z+(RT)*t2_.z,0.f)*w2_.z + fmaxf(A[11]+b2_.w+(RT)*t2_.w,0.f)*w2_.w \
       + fmaxf(A[12]+b3_.x+(RT)*t3_.x,0.f)*w3_.x + fmaxf(A[13]+b3_.y+(RT)*t3_.y,0.f)*w3_.y \
       + fmaxf(A[14]+b3_.z+(RT)*t3_.z,0.f)*w3_.z + fmaxf(A[15]+b3_.w+(RT)*t3_.w,0.f)*w3_.w; }

__global__ __launch_bounds__(NT, 2)
void drnet_main(const float* __restrict__ t, const float* __restrict__ x,
                const float* __restrict__ db1, const float* __restrict__ db2,
                const float* __restrict__ hb1, const float* __restrict__ htw1,
                const float* __restrict__ hb2, const float* __restrict__ htw2,
                const float* __restrict__ hw3, const float* __restrict__ htw3,
                const float* __restrict__ hb3,
                const f16x8* __restrict__ pw,
                float* __restrict__ out, int N, int NG)
{
    __shared__ __align__(16) f16x8 swts[NENT];          // 102 KB: all weight frags
    __shared__ __align__(16) float sb1f[64], sb2f[64];
    __shared__ __align__(16) float shb1[NB*64], shw1t[NB*64], shb2[NB*64], shw2t[NB*64], sw3f[NB*64];
    __shared__ float shtw3[NB], shb3[NB];
    __shared__ unsigned short ssrt[8][64];
    __shared__ float sstv[8][64];
    __shared__ float sout[8][64];

    const int tid = threadIdx.x;
    const int lane = tid & 63;
    const int wv = tid >> 6;
    const int hi = lane >> 5;
    const int sm = lane & 31;
    const bool lo = (hi == 0);

    for (int p = tid; p < 64; p += NT) { sb1f[p] = db1[p]; sb2f[p] = db2[p]; }
    for (int p = tid; p < NB*64; p += NT) {
        shb1[p] = hb1[p]; shw1t[p] = htw1[p];
        shb2[p] = hb2[p]; shw2t[p] = htw2[p];
        sw3f[p] = hw3[p];
    }
    if (tid < NB) { shtw3[tid] = htw3[tid]; shb3[tid] = hb3[tid]; }
    for (int p = tid; p < NENT; p += NT)
        ((float4*)swts)[p] = ((const float4*)pw)[p];
    __syncthreads();   // ONLY barrier; the main loop is fully wave-autonomous

    #define TF(fid) swts[(fid)*64 + lane]

    auto do_tile = [&](const f16x8* xb, int li, int rq, float rt, int qlo, int qhiR) {
        if (qlo >= NB) return;
        const int qhi = min(qhiR, NB - 1);

        f32x16 a0 = vzero(), a1 = vzero();
        #pragma unroll
        for (int ks = 0; ks < 7; ++ks) {
            a0 = mfma32(TF(ks*2 + 0), xb[ks], a0);
            a1 = mfma32(TF(ks*2 + 1), xb[ks], a1);
        }
        unsigned WA[8], WB[8];
        EPI8B(WA, a0, sb1f, 4*hi);
        EPI8B(WB, a1, sb1f, 32 + 4*hi);
        f16x8 hb0, hb1_, hb2_, hb3_;
        MKB(hb0, WA, 0); MKB(hb1_, WA, 4); MKB(hb2_, WB, 0); MKB(hb3_, WB, 4);

        f32x16 c0 = vzero(), c1 = vzero();
        c0 = mfma32(TF(FID_W2+0), hb0, c0);  c1 = mfma32(TF(FID_W2+1), hb0, c1);
        c0 = mfma32(TF(FID_W2+2), hb1_, c0); c1 = mfma32(TF(FID_W2+3), hb1_, c1);
        c0 = mfma32(TF(FID_W2+4), hb2_, c0); c1 = mfma32(TF(FID_W2+5), hb2_, c1);
        c0 = mfma32(TF(FID_W2+6), hb3_, c0); c1 = mfma32(TF(FID_W2+7), hb3_, c1);
        unsigned UA[8], UB[8];
        EPI8B(UA, c0, sb2f, 4*hi);
        EPI8B(UB, c1, sb2f, 32 + 4*hi);
        f16x8 g0, g1, g2, g3;
        MKB(g0, UA, 0); MKB(g1, UA, 4); MKB(g2, UB, 0); MKB(g3, UB, 4);

        #pragma unroll 1
        for (int q = qlo; q <= qhi; ++q) {
            const int hf = FID_HD + q * 16;
            f32x16 d0 = vzero(), d1 = vzero();
            d0 = mfma32(TF(hf+0), g0, d0);  d1 = mfma32(TF(hf+1), g0, d1);
            d0 = mfma32(TF(hf+2), g1, d0);  d1 = mfma32(TF(hf+3), g1, d1);
            d0 = mfma32(TF(hf+4), g2, d0);  d1 = mfma32(TF(hf+5), g2, d1);
            d0 = mfma32(TF(hf+6), g3, d0);  d1 = mfma32(TF(hf+7), g3, d1);
            unsigned VA[8], VB[8];
            EPI8T(VA, d0, shb1 + q*64, shw1t + q*64, rt, 4*hi);
            EPI8T(VB, d1, shb1 + q*64, shw1t + q*64, rt, 32 + 4*hi);
            f16x8 e0, e1, e2, e3;
            MKB(e0, VA, 0); MKB(e1, VA, 4); MKB(e2, VB, 0); MKB(e3, VB, 4);

            f32x16 f0 = vzero(), f1 = vzero();
            f0 = mfma32(TF(hf+8),  e0, f0);  f1 = mfma32(TF(hf+9),  e0, f1);
            f0 = mfma32(TF(hf+10), e1, f0);  f1 = mfma32(TF(hf+11), e1, f1);
            f0 = mfma32(TF(hf+12), e2, f0);  f1 = mfma32(TF(hf+13), e2, f1);
            f0 = mfma32(TF(hf+14), e3, f0);  f1 = mfma32(TF(hf+15), e3, f1);

            float part = 0.f;
            ACC16(part, f0, shb2 + q*64, shw2t + q*64, sw3f + q*64, rt, 4*hi);
            ACC16(part, f1, shb2 + q*64, shw2t + q*64, sw3f + q*64, rt, 32 + 4*hi);
            part += __shfl_xor(part, 32, 64);
            if (lo && rq == q)
                sout[wv][li] = part + rt * shtw3[q] + shb3[q];
        }
    };

    auto sortw = [&](int gn, float tvn) {
        const int i0 = gn * 64 + lane;
        const int qme = (i0 < N) ? min((int)(tvn * 5.0f), NB - 1) : NB;
        const u64 lowm = (1ull << lane) - 1ull;
        int pos = 0;
        #pragma unroll
        for (int b = 0; b <= NB; ++b) {
            u64 mb = __ballot(qme == b);
            int ca = __popcll(mb), cb = __popcll(mb & lowm);
            pos += (b < qme) ? ca : ((b == qme) ? cb : 0);
        }
        ssrt[wv][pos] = (unsigned short)(lane | (qme << 8));
        sstv[wv][pos] = tvn;
        __asm__ volatile("s_waitcnt lgkmcnt(0)" ::: "memory");
    };

    auto issue_x = [&](float4* r, int gn, int li) {
        const float4* xp = (const float4*)(x + (size_t)min(gn * 64 + li, N - 1) * DIN);
        #pragma unroll
        for (int ks = 0; ks < 6; ++ks) { r[2*ks] = xp[4*ks + 2*hi]; r[2*ks+1] = xp[4*ks + 2*hi + 1]; }
        r[12] = lo ? xp[24] : make_float4(0.f, 0.f, 0.f, 0.f);
    };

    auto convert = [&](f16x8* xb, const float4* r) {
        #pragma unroll
        for (int ks = 0; ks < 6; ++ks)
            xb[ks] = frag4(pk2(r[2*ks].x, r[2*ks].y),   pk2(r[2*ks].z, r[2*ks].w),
                           pk2(r[2*ks+1].x, r[2*ks+1].y), pk2(r[2*ks+1].z, r[2*ks+1].w));
        xb[6] = frag4(pk2(r[12].x, r[12].y), pk2(r[12].z, r[12].w), 0u, 0u);
    };

    const int gw = blockIdx.x * 8 + wv;
    const int S = NWAVES;

    float4 raw0[13], raw1[13];
    float treg = 0.f;
    int g = gw;
    if (g < NG) {
        treg = t[min(g * 64 + lane, N - 1)];
        sortw(g, treg);                                   // window g sorted
        { int li = ssrt[wv][sm] & 63; issue_x(raw0, g, li); }   // T0(g) in flight
        { int gn = g + S; treg = (gn < NG) ? t[min(gn * 64 + lane, N - 1)] : 0.f; }
    }

    // INVARIANT at loop top: ssrt/sstv = window g; raw0 = T0(g) in flight; treg = t(g+S)
    #pragma unroll 1
    for (; g < NG; g += S) {
        const unsigned short pk0 = ssrt[wv][sm], pk1 = ssrt[wv][32 + sm];
        const int li0 = pk0 & 63, rq0 = pk0 >> 8;
        const int li1 = pk1 & 63, rq1 = pk1 >> 8;
        const float rt0 = sstv[wv][sm], rt1 = sstv[wv][32 + sm];
        const int qlo0 = ssrt[wv][0]  >> 8, qh0 = ssrt[wv][31] >> 8;
        const int qlo1 = ssrt[wv][32] >> 8, qh1 = ssrt[wv][63] >> 8;

        issue_x(raw1, g, li1);                 // T1(g) loads join the queue first
        f16x8 xb0[7], xb1[7];
        convert(xb0, raw0);                    // waits raw0 only (raw1 stays in flight)
        __builtin_amdgcn_sched_barrier(0);     // pin: loads issued before tile0 compute
        do_tile(xb0, li0, rq0, rt0, qlo0, qh0);
        __builtin_amdgcn_sched_barrier(0);     // pin: raw1 wait not hoisted above tile0

        const bool last = (g + S >= NG);
        if (!last) {
            sortw(g + S, treg);                // next window's sort (t prefetched 1 window ago)
            { int gn2 = g + 2 * S; treg = (gn2 < NG) ? t[min(gn2 * 64 + lane, N - 1)] : 0.f; }
            { int li = ssrt[wv][sm] & 63; issue_x(raw0, g + S, li); }  // T0(g+S) in flight
            __builtin_amdgcn_sched_barrier(0); // pin: next-window loads issued before tile1
        }
        convert(xb1, raw1);                    // counted wait: raw0(next) stays in flight
        do_tile(xb1, li1, rq1, rt1, qlo1, qh1);

        __asm__ volatile("s_waitcnt lgkmcnt(0)" ::: "memory");
        const int ig = g * 64 + lane;
        if (ig < N) out[ig] = sout[wv][lane];  // coalesced flush
    }
    #undef TF
}

extern "C" void kernel_launch(void* const* d_in, const int* in_sizes, int n_in,
                              void* d_out, int out_size, void* d_ws, size_t ws_size,
                              hipStream_t stream) {
    const float* t    = (const float*)d_in[0];
    const float* x    = (const float*)d_in[1];
    const float* dW1  = (const float*)d_in[2];
    const float* db1  = (const float*)d_in[3];
    const float* dW2  = (const float*)d_in[4];
    const float* db2  = (const float*)d_in[5];
    const float* hw1  = (const float*)d_in[6];
    const float* htw1 = (const float*)d_in[7];
    const float* hb1  = (const float*)d_in[8];
    const float* hw2  = (const float*)d_in[9];
    const float* htw2 = (const float*)d_in[10];
    const float* hb2  = (const float*)d_in[11];
    const float* hw3  = (const float*)d_in[12];
    const float* htw3 = (const float*)d_in[13];
    const float* hb3  = (const float*)d_in[14];
    float* out = (float*)d_out;

    const int N = in_sizes[0];
    const int NG = (N + 63) / 64;
    f16x8* pw = (f16x8*)d_ws;   // NENT * 16 B = 104,448 B

    prepack_kernel<<<(NENT + 255) / 256, 256, 0, stream>>>(dW1, dW2, hw1, hw2, pw);
    drnet_main<<<GRID, NT, 0, stream>>>(t, x, db1, db2, hb1, htw1, hb2, htw2,
                                        hw3, htw3, hb3, pw, out, N, NG);
}